// Round 6
// baseline (134.912 us; speedup 1.0000x reference)
//
#include <hip/hip_runtime.h>
#include <hip/hip_bf16.h>
#include <math.h>

#define BB 64
#define NN 64
#define HH 256
#define FF 8

typedef __bf16 bf16;
typedef bf16 bf16x2 __attribute__((ext_vector_type(2)));
typedef bf16 bf16x4 __attribute__((ext_vector_type(4)));
typedef bf16 bf16x8 __attribute__((ext_vector_type(8)));
typedef float f32x2 __attribute__((ext_vector_type(2)));
typedef float f32x4 __attribute__((ext_vector_type(4)));

// async global->LDS, 16B per lane, wave-uniform LDS base + lane*16
#define GLL(g, l) __builtin_amdgcn_global_load_lds( \
    (const __attribute__((address_space(1))) void*)(g), \
    (__attribute__((address_space(3))) void*)(l), 16, 0, 0)

#define MFMA(a, b, c) __builtin_amdgcn_mfma_f32_16x16x32_bf16(a, b, c, 0, 0, 0)

__device__ __forceinline__ f32x2 unpk(unsigned int u) {
    union { unsigned int i; float f; } a, b;
    a.i = (u & 0xffffu) << 16;
    b.i = u & 0xffff0000u;
    f32x2 r; r.x = a.f; r.y = b.f; return r;
}

// MFMA fragment from global: elems k = l4*4+{0..3} and +16, contiguous pairs.
__device__ __forceinline__ bf16x8 ldfrag(const bf16* p) {
    bf16x4 lo = *(const bf16x4*)p;
    bf16x4 hi = *(const bf16x4*)(p + 16);
    return __builtin_shufflevector(lo, hi, 0, 1, 2, 3, 4, 5, 6, 7);
}

// MFMA A-fragment from swizzled LDS tile [rows][256] bf16 (512 B rows).
__device__ __forceinline__ bf16x8 ldfrag_lds(const char* base, int row, int cbyte) {
    const int sw = (row & 7) << 4;
    const int a = row * 512 + cbyte;
    bf16x4 lo = *(const bf16x4*)(base + (a ^ sw));
    bf16x4 hi = *(const bf16x4*)(base + ((a + 32) ^ sw));
    return __builtin_shufflevector(lo, hi, 0, 1, 2, 3, 4, 5, 6, 7);
}

__device__ __forceinline__ void st_lds(char* base, int row, int col, bf16 v) {
    *(bf16*)(base + ((row * 512 + col * 2) ^ ((row & 7) << 4))) = v;
}

// ---------------------------------------------------------------------------
// Pack kernel v2: LDS-tiled transposes (coalesced both sides) + hbf convert.
// Blocks 0..175: weight transposes, dst[n*R + k] = src[k*C + n]
//   0..63  : ed_w1 halves -> W1t   (R=256, C=512), 32 tiles each
//   64..95 : ed_w2        -> W2t   (R=512, C=256)
//   96..175: wr,wi,wh,f1_w,f2_w -> Wg(3), f1t, f2t (R=C=256), 16 tiles each
// Blocks 176..1199: hbf = bf16(hidden).
// ---------------------------------------------------------------------------
__global__ __launch_bounds__(256) void pack_kernel(
    const float* __restrict__ hidden,
    const float* __restrict__ ed_w1, const float* __restrict__ ed_w2,
    const float* __restrict__ wr, const float* __restrict__ wi,
    const float* __restrict__ wh,
    const float* __restrict__ f1_w, const float* __restrict__ f2_w,
    bf16* __restrict__ hbf, bf16* __restrict__ W1t, bf16* __restrict__ W2t,
    bf16* __restrict__ Wg, bf16* __restrict__ f1t, bf16* __restrict__ f2t)
{
    const int t = blockIdx.x;
    const int tid = threadIdx.x;

    if (t >= 176) {  // hbf convert
        int i = (t - 176) * 1024 + tid * 4;
        float4 v = *(const float4*)(hidden + i);
        bf16x4 o;
        o[0] = (bf16)v.x; o[1] = (bf16)v.y; o[2] = (bf16)v.z; o[3] = (bf16)v.w;
        *(bf16x4*)(hbf + i) = o;
        return;
    }

    const float* src; bf16* dst; int R, C, tile;
    if (t < 64) {
        src = ed_w1 + (t >= 32 ? 131072 : 0);
        dst = W1t + (t >= 32 ? 131072 : 0);
        R = 256; C = 512; tile = t & 31;
    } else if (t < 96) {
        src = ed_w2; dst = W2t; R = 512; C = 256; tile = t - 64;
    } else {
        int m = (t - 96) >> 4; tile = (t - 96) & 15; R = 256; C = 256;
        const float* ss[5] = {wr, wi, wh, f1_w, f2_w};
        bf16* dd[5] = {Wg, Wg + 65536, Wg + 131072, f1t, f2t};
        src = ss[m]; dst = dd[m];
    }
    const int tc = C >> 6;
    const int k0 = (tile / tc) * 64, n0 = (tile % tc) * 64;

    __shared__ float ls[64][65];
    {
        int rr = tid >> 2, cc = (tid & 3) * 16;
        const float* sp = src + (size_t)(k0 + rr) * C + n0 + cc;
#pragma unroll
        for (int j = 0; j < 16; j += 4) {
            float4 v = *(const float4*)(sp + j);
            ls[rr][cc + j] = v.x; ls[rr][cc + j + 1] = v.y;
            ls[rr][cc + j + 2] = v.z; ls[rr][cc + j + 3] = v.w;
        }
    }
    __syncthreads();
    {
        int n = tid >> 2, kc = (tid & 3) * 16;
        bf16x8 o0, o1;
#pragma unroll
        for (int j = 0; j < 8; ++j) o0[j] = (bf16)ls[kc + j][n];
#pragma unroll
        for (int j = 0; j < 8; ++j) o1[j] = (bf16)ls[kc + 8 + j][n];
        bf16* dp = dst + (size_t)(n0 + n) * R + k0 + kc;
        *(bf16x8*)dp = o0;
        *(bf16x8*)(dp + 8) = o1;
    }
}

// ---------------------------------------------------------------------------
// G1 MFMA GEMM (proven structure): tile 64x64, 4 waves, BK=64, dbuf LDS.
// Cb = bf16(A@B); A [M][K] bf16, Bt [N][K] bf16.
// ---------------------------------------------------------------------------
__global__ __launch_bounds__(256) void g1_gemm(
    const bf16* __restrict__ A, const bf16* __restrict__ Bt,
    bf16* __restrict__ Cb, int N, int K)
{
    constexpr int ASZ = 64 * 64 * 2;
    __shared__ __align__(1024) char smem[4 * ASZ];

    const int tid  = threadIdx.x;
    const int wave = tid >> 6, lane = tid & 63;
    const int wr_  = wave >> 1, wc_ = wave & 1;
    const int l15  = lane & 15, l4 = lane >> 4;
    const int bm   = blockIdx.y * 64, bn = blockIdx.x * 64;

    const int srow = lane >> 3;
    const int scol = ((lane & 7) ^ (lane >> 3)) * 8;

    f32x4 acc[2][2];
#pragma unroll
    for (int mf = 0; mf < 2; ++mf)
#pragma unroll
        for (int nf = 0; nf < 2; ++nf)
            acc[mf][nf] = (f32x4){0.f, 0.f, 0.f, 0.f};

    auto stage = [&](int buf, int kt) {
        char* base = smem + buf * 2 * ASZ;
#pragma unroll
        for (int si = 0; si < 4; ++si) {
            int s = wave * 4 + si;
            char* ldst = base + s * 1024 + lane * 16;
            const bf16* g;
            if (s < 8) {
                g = A + ((size_t)(bm + s * 8 + srow) * K + kt * 64 + scol);
            } else {
                int r8 = s - 8;
                g = Bt + (size_t)(bn + r8 * 8 + srow) * K + kt * 64 + scol;
            }
            GLL(g, ldst);
        }
    };

    auto compute = [&](int buf) {
        char* base = smem + buf * 2 * ASZ;
#pragma unroll
        for (int kk = 0; kk < 2; ++kk) {
            bf16x8 af[2];
#pragma unroll
            for (int mf = 0; mf < 2; ++mf) {
                int row = wr_ * 32 + mf * 16 + l15;
                int c0 = row * 128 + kk * 64 + l4 * 8;
                int sw = (row & 7) << 4;
                bf16x4 lo = *(const bf16x4*)(base + (c0 ^ sw));
                bf16x4 hi = *(const bf16x4*)(base + ((c0 + 32) ^ sw));
                af[mf] = __builtin_shufflevector(lo, hi, 0, 1, 2, 3, 4, 5, 6, 7);
            }
#pragma unroll
            for (int nf = 0; nf < 2; ++nf) {
                int row = wc_ * 32 + nf * 16 + l15;
                int c0 = row * 128 + kk * 64 + l4 * 8;
                int sw = (row & 7) << 4;
                const char* bb = base + ASZ;
                bf16x4 lo = *(const bf16x4*)(bb + (c0 ^ sw));
                bf16x4 hi = *(const bf16x4*)(bb + ((c0 + 32) ^ sw));
                bf16x8 bfr = __builtin_shufflevector(lo, hi, 0, 1, 2, 3, 4, 5, 6, 7);
#pragma unroll
                for (int mf = 0; mf < 2; ++mf)
                    acc[mf][nf] = MFMA(af[mf], bfr, acc[mf][nf]);
            }
        }
    };

    const int nt = K / 64;
    stage(0, 0);
    __syncthreads();
    for (int t = 0; t < nt; ++t) {
        if (t + 1 < nt) stage((t + 1) & 1, t + 1);
        compute(t & 1);
        __syncthreads();
    }

#pragma unroll
    for (int mf = 0; mf < 2; ++mf)
#pragma unroll
        for (int nf = 0; nf < 2; ++nf)
#pragma unroll
            for (int r = 0; r < 4; ++r) {
                int grow = bm + wr_ * 32 + mf * 16 + l4 * 4 + r;
                int col = bn + wc_ * 32 + nf * 16 + l15;
                Cb[(size_t)grow * N + col] = (bf16)acc[mf][nf][r];
            }
}

// ---------------------------------------------------------------------------
// Edge aggregation v4 (unchanged): packed channel pairs, 1024 blocks.
// ---------------------------------------------------------------------------
__global__ __launch_bounds__(256) void edge_agg_kernel(
    const bf16* __restrict__ PQ, const float* __restrict__ edges,
    const float* __restrict__ b1, bf16* __restrict__ S)
{
    const int blk = blockIdx.x;
    const int dgrp = blk & 15;
    const int b = blk >> 4;
    const int tid = threadIdx.x;
    const int d0 = dgrp * 4;

    __shared__ __align__(16) float wls[64][4];
    {
        int src = tid >> 2, dd = tid & 3;
        int d = d0 + dd;
        float w = 0.f;
        if (src != d) {
            int e = src * 63 + (d < src ? d : d - 1);
            float2 ev = ((const float2*)edges)[e];
            w = fmaxf(ev.x, ev.y);
        }
        wls[src][dd] = w;
    }
    __syncthreads();

    const bf16* Pb = PQ + (size_t)(b * 64) * 1024;
    f32x2 p2[4];
#pragma unroll
    for (int dd = 0; dd < 4; ++dd)
        p2[dd] = unpk(*(const unsigned int*)(Pb + (size_t)(d0 + dd) * 1024 + 2 * tid));
    float2 bbl = *(const float2*)(b1 + 2 * tid);
    f32x2 bb; bb.x = bbl.x; bb.y = bbl.y;
    const unsigned int* Qp = (const unsigned int*)(Pb + 512) + tid;

    f32x2 acc[4];
#pragma unroll
    for (int dd = 0; dd < 4; ++dd) acc[dd] = (f32x2){0.f, 0.f};

#pragma unroll 4
    for (int src = 0; src < 64; ++src) {
        f32x2 q = unpk(Qp[(size_t)src * 512]);
        float4 wv = *(const float4*)&wls[src][0];
        float w[4] = {wv.x, wv.y, wv.z, wv.w};
#pragma unroll
        for (int dd = 0; dd < 4; ++dd) {
            f32x2 w2; w2.x = w[dd]; w2.y = w[dd];
            f32x2 v = (p2[dd] + q) * w2 + bb;
            float e0 = __expf(v.x) - 1.f;
            float e1 = __expf(v.y) - 1.f;
            f32x2 r;
            r.x = (v.x > 0.f) ? v.x : e0;
            r.y = (v.y > 0.f) ? v.y : e1;
            acc[dd] += r;
        }
    }
    f32x2 selfc;
    selfc.x = (bb.x > 0.f) ? bb.x : (__expf(bb.x) - 1.f);
    selfc.y = (bb.y > 0.f) ? bb.y : (__expf(bb.y) - 1.f);
#pragma unroll
    for (int dd = 0; dd < 4; ++dd) {
        bf16x2 st;
        st[0] = (bf16)(acc[dd].x - selfc.x);
        st[1] = (bf16)(acc[dd].y - selfc.y);
        *(bf16x2*)(S + (size_t)(b * 64 + d0 + dd) * 512 + 2 * tid) = st;
    }
}

// ---------------------------------------------------------------------------
// FUSE2: agg GEMM (K=512) + 3 gate GEMMs (K=256) + GRU epilogue.
// 128 blocks x 512 threads; 32-row stripe per block; wave w owns cols
// [w*32, w*32+32). B-fragments read directly from global (L2-resident).
// ---------------------------------------------------------------------------
__global__ __launch_bounds__(512) void fuse_gru_kernel(
    const bf16* __restrict__ Sb, const bf16* __restrict__ W2t,
    const float* __restrict__ ed_b2, const bf16* __restrict__ Wg,
    const float* __restrict__ inputs, const float* __restrict__ hidden,
    const float* __restrict__ irw, const float* __restrict__ irb,
    const float* __restrict__ iiw, const float* __restrict__ iib,
    const float* __restrict__ inw, const float* __restrict__ inb,
    float* __restrict__ NH, bf16* __restrict__ NHb)
{
    __shared__ __align__(16) char aggl[32 * 512];   // [32][256] bf16, swizzled
    const int tid = threadIdx.x;
    const int wave = tid >> 6, lane = tid & 63;
    const int l15 = lane & 15, l4 = lane >> 4;
    const int m0 = blockIdx.x * 32;
    const int n0 = wave * 32;

    // ---- stage 1: agg = Sb stripe @ W2 /63 + b2 ----
    f32x4 acc1[2][2];
#pragma unroll
    for (int mf = 0; mf < 2; ++mf)
#pragma unroll
        for (int nf = 0; nf < 2; ++nf)
            acc1[mf][nf] = (f32x4){0.f, 0.f, 0.f, 0.f};

    const bf16* a0p = Sb + (size_t)(m0 + l15) * 512 + l4 * 4;
    const bf16* a1p = a0p + 16 * 512;
#pragma unroll
    for (int ks = 0; ks < 16; ++ks) {
        bf16x8 afa = ldfrag(a0p + ks * 32);
        bf16x8 afb = ldfrag(a1p + ks * 32);
#pragma unroll
        for (int nf = 0; nf < 2; ++nf) {
            bf16x8 bf_ = ldfrag(W2t + (size_t)(n0 + nf * 16 + l15) * 512 + ks * 32 + l4 * 4);
            acc1[0][nf] = MFMA(afa, bf_, acc1[0][nf]);
            acc1[1][nf] = MFMA(afb, bf_, acc1[1][nf]);
        }
    }
#pragma unroll
    for (int mf = 0; mf < 2; ++mf)
#pragma unroll
        for (int nf = 0; nf < 2; ++nf) {
            int col = n0 + nf * 16 + l15;
            float eb = ed_b2[col];
#pragma unroll
            for (int r = 0; r < 4; ++r) {
                int row = mf * 16 + l4 * 4 + r;
                st_lds(aggl, row, col, (bf16)(acc1[mf][nf][r] * (1.f / 63.f) + eb));
            }
        }
    __syncthreads();

    // ---- stage 2: gates[g] = agg @ wg (K=256), A from LDS ----
    f32x4 acc2[3][2][2];
#pragma unroll
    for (int g = 0; g < 3; ++g)
#pragma unroll
        for (int mf = 0; mf < 2; ++mf)
#pragma unroll
            for (int nf = 0; nf < 2; ++nf)
                acc2[g][mf][nf] = (f32x4){0.f, 0.f, 0.f, 0.f};

#pragma unroll
    for (int ks = 0; ks < 8; ++ks) {
        const int cb = ks * 64 + l4 * 8;
        bf16x8 afa = ldfrag_lds(aggl, l15, cb);
        bf16x8 afb = ldfrag_lds(aggl, 16 + l15, cb);
#pragma unroll
        for (int g = 0; g < 3; ++g)
#pragma unroll
            for (int nf = 0; nf < 2; ++nf) {
                bf16x8 bf_ = ldfrag(Wg + (size_t)g * 65536
                                    + (size_t)(n0 + nf * 16 + l15) * 256 + ks * 32 + l4 * 4);
                acc2[g][0][nf] = MFMA(afa, bf_, acc2[g][0][nf]);
                acc2[g][1][nf] = MFMA(afb, bf_, acc2[g][1][nf]);
            }
    }

    // ---- GRU epilogue ----
#pragma unroll
    for (int nf = 0; nf < 2; ++nf) {
        const int col = n0 + nf * 16 + l15;
        float w8r[8], w8i[8], w8n[8];
#pragma unroll
        for (int f = 0; f < 8; ++f) {
            w8r[f] = irw[f * 256 + col];
            w8i[f] = iiw[f * 256 + col];
            w8n[f] = inw[f * 256 + col];
        }
        const float xr0 = irb[col], xi0 = iib[col], xn0 = inb[col];
#pragma unroll
        for (int mf = 0; mf < 2; ++mf)
#pragma unroll
            for (int r = 0; r < 4; ++r) {
                const int grow = m0 + mf * 16 + l4 * 4 + r;
                const float* inp = inputs + (size_t)grow * 8;
                float xr = xr0, xi = xi0, xn = xn0;
#pragma unroll
                for (int f = 0; f < 8; ++f) {
                    float x = inp[f];
                    xr += x * w8r[f]; xi += x * w8i[f]; xn += x * w8n[f];
                }
                float aR = acc2[0][mf][nf][r];
                float aI = acc2[1][mf][nf][r];
                float aN = acc2[2][mf][nf][r];
                float rg = __builtin_amdgcn_rcpf(1.f + __expf(-(xr + aR)));
                float ig = __builtin_amdgcn_rcpf(1.f + __expf(-(xi + aI)));
                float tz = xn + rg * aN;
                tz = fminf(fmaxf(tz, -15.f), 15.f);
                float e2x = __expf(2.f * tz);
                float nn = (e2x - 1.f) * __builtin_amdgcn_rcpf(e2x + 1.f);
                size_t o = (size_t)grow * 256 + col;
                float nh = (1.f - ig) * nn + ig * hidden[o];
                NH[o] = nh;
                NHb[o] = (bf16)nh;
            }
    }
}

// ---------------------------------------------------------------------------
// FUSE3: H1 = relu(NH@f1+b) -> H2 = relu(H1@f2+b) -> pred = in + H2@f3+b.
// 128 blocks x 512 threads; 32-row stripes; intermediates in swizzled LDS.
// ---------------------------------------------------------------------------
__global__ __launch_bounds__(512) void fuse_mlp_kernel(
    const bf16* __restrict__ NHb, const bf16* __restrict__ f1t,
    const float* __restrict__ f1_b, const bf16* __restrict__ f2t,
    const float* __restrict__ f2_b, const float* __restrict__ f3_w,
    const float* __restrict__ f3_b, const float* __restrict__ inputs,
    float* __restrict__ pred)
{
    __shared__ __align__(16) char h1l[32 * 512];
    __shared__ __align__(16) char h2l[32 * 512];
    __shared__ float f3s[2048];
    const int tid = threadIdx.x;
    const int wave = tid >> 6, lane = tid & 63;
    const int l15 = lane & 15, l4 = lane >> 4;
    const int m0 = blockIdx.x * 32;
    const int n0 = wave * 32;

    for (int i = tid; i < 2048; i += 512) f3s[i] = f3_w[i];

    // ---- stage 1 ----
    f32x4 acc[2][2];
#pragma unroll
    for (int mf = 0; mf < 2; ++mf)
#pragma unroll
        for (int nf = 0; nf < 2; ++nf)
            acc[mf][nf] = (f32x4){0.f, 0.f, 0.f, 0.f};
    {
        const bf16* a0p = NHb + (size_t)(m0 + l15) * 256 + l4 * 4;
        const bf16* a1p = a0p + 16 * 256;
#pragma unroll
        for (int ks = 0; ks < 8; ++ks) {
            bf16x8 afa = ldfrag(a0p + ks * 32);
            bf16x8 afb = ldfrag(a1p + ks * 32);
#pragma unroll
            for (int nf = 0; nf < 2; ++nf) {
                bf16x8 bf_ = ldfrag(f1t + (size_t)(n0 + nf * 16 + l15) * 256 + ks * 32 + l4 * 4);
                acc[0][nf] = MFMA(afa, bf_, acc[0][nf]);
                acc[1][nf] = MFMA(afb, bf_, acc[1][nf]);
            }
        }
#pragma unroll
        for (int mf = 0; mf < 2; ++mf)
#pragma unroll
            for (int nf = 0; nf < 2; ++nf) {
                int col = n0 + nf * 16 + l15;
                float b = f1_b[col];
#pragma unroll
                for (int r = 0; r < 4; ++r)
                    st_lds(h1l, mf * 16 + l4 * 4 + r, col,
                           (bf16)fmaxf(acc[mf][nf][r] + b, 0.f));
            }
    }
    __syncthreads();

    // ---- stage 2 ----
#pragma unroll
    for (int mf = 0; mf < 2; ++mf)
#pragma unroll
        for (int nf = 0; nf < 2; ++nf)
            acc[mf][nf] = (f32x4){0.f, 0.f, 0.f, 0.f};
#pragma unroll
    for (int ks = 0; ks < 8; ++ks) {
        const int cb = ks * 64 + l4 * 8;
        bf16x8 afa = ldfrag_lds(h1l, l15, cb);
        bf16x8 afb = ldfrag_lds(h1l, 16 + l15, cb);
#pragma unroll
        for (int nf = 0; nf < 2; ++nf) {
            bf16x8 bf_ = ldfrag(f2t + (size_t)(n0 + nf * 16 + l15) * 256 + ks * 32 + l4 * 4);
            acc[0][nf] = MFMA(afa, bf_, acc[0][nf]);
            acc[1][nf] = MFMA(afb, bf_, acc[1][nf]);
        }
    }
#pragma unroll
    for (int mf = 0; mf < 2; ++mf)
#pragma unroll
        for (int nf = 0; nf < 2; ++nf) {
            int col = n0 + nf * 16 + l15;
            float b = f2_b[col];
#pragma unroll
            for (int r = 0; r < 4; ++r)
                st_lds(h2l, mf * 16 + l4 * 4 + r, col,
                       (bf16)fmaxf(acc[mf][nf][r] + b, 0.f));
        }
    __syncthreads();

    // ---- stage 3: pred ----
    if (tid < 256) {
        const int row = tid >> 3, f = tid & 7;
        const int sw = (row & 7) << 4;
        float a = f3_b[f];
        for (int k0 = 0; k0 < 256; k0 += 8) {
            bf16x8 h8 = *(const bf16x8*)(h2l + ((row * 512 + k0 * 2) ^ sw));
#pragma unroll
            for (int j = 0; j < 8; ++j)
                a += (float)h8[j] * f3s[(k0 + j) * 8 + f];
        }
        int gi = (m0 + row) * 8 + f;
        pred[gi] = inputs[gi] + a;
    }
}

// ---------------------------------------------------------------------------
extern "C" void kernel_launch(void* const* d_in, const int* in_sizes, int n_in,
                              void* d_out, int out_size, void* d_ws, size_t ws_size,
                              hipStream_t stream) {
    const float* inputs = (const float*)d_in[0];
    const float* hidden = (const float*)d_in[1];
    const float* edges  = (const float*)d_in[2];
    const float* ed_w1 = (const float*)d_in[4];
    const float* ed_b1 = (const float*)d_in[5];
    const float* ed_w2 = (const float*)d_in[6];
    const float* ed_b2 = (const float*)d_in[7];
    const float* wr = (const float*)d_in[8];
    const float* wi = (const float*)d_in[9];
    const float* wh = (const float*)d_in[10];
    const float* ir_w = (const float*)d_in[11];
    const float* ir_b = (const float*)d_in[12];
    const float* ii_w = (const float*)d_in[13];
    const float* ii_b = (const float*)d_in[14];
    const float* in_w = (const float*)d_in[15];
    const float* in_b = (const float*)d_in[16];
    const float* f1_w = (const float*)d_in[17];
    const float* f1_b = (const float*)d_in[18];
    const float* f2_w = (const float*)d_in[19];
    const float* f2_b = (const float*)d_in[20];
    const float* f3_w = (const float*)d_in[21];
    const float* f3_b = (const float*)d_in[22];

    float* out = (float*)d_out;
    float* pred = out;
    float* NH = out + (size_t)BB * NN * FF;

    // bf16 workspace layout (element offsets)
    bf16* bws = (bf16*)d_ws;
    bf16* PQ   = bws;              // 4096*1024
    bf16* Sb   = bws + 4194304;    // 4096*512
    bf16* NHb  = bws + 6291456;    // 4096*256
    bf16* hbf  = bws + 7340032;    // 4096*256
    bf16* W1t  = bws + 8388608;    // 1024*256
    bf16* W2t  = bws + 8650752;    // 256*512
    bf16* Wg   = bws + 8781824;    // 3*256*256
    bf16* f1t  = bws + 8978432;    // 256*256
    bf16* f2t  = bws + 9043968;    // 256*256

    dim3 blk(256);

    pack_kernel<<<dim3(1200), blk, 0, stream>>>(
        hidden, ed_w1, ed_w2, wr, wi, wh, f1_w, f2_w,
        hbf, W1t, W2t, Wg, f1t, f2t);

    // G1: PQ = hidden @ [W1top | W1bot]   (4096,1024,256)
    g1_gemm<<<dim3(16, 64), blk, 0, stream>>>(hbf, W1t, PQ, 1024, 256);

    // S: per-(b,d) elu-sum over sources
    edge_agg_kernel<<<dim3(1024), blk, 0, stream>>>(PQ, edges, ed_b1, Sb);

    // FUSE2: agg + gates + GRU -> NH, NHb
    fuse_gru_kernel<<<dim3(128), dim3(512), 0, stream>>>(
        Sb, W2t, ed_b2, Wg, inputs, hidden,
        ir_w, ir_b, ii_w, ii_b, in_w, in_b, NH, NHb);

    // FUSE3: f1 -> f2 -> pred
    fuse_mlp_kernel<<<dim3(128), dim3(512), 0, stream>>>(
        NHb, f1t, f1_b, f2t, f2_b, f3_w, f3_b, inputs, pred);
}

// Round 7
// 81.310 us; speedup vs baseline: 1.6592x; 1.6592x over previous
//
#include <hip/hip_runtime.h>
#include <hip/hip_bf16.h>
#include <math.h>

#define BB 64
#define NN 64
#define HH 256
#define FF 8

typedef __bf16 bf16;
typedef bf16 bf16x2 __attribute__((ext_vector_type(2)));
typedef bf16 bf16x4 __attribute__((ext_vector_type(4)));
typedef bf16 bf16x8 __attribute__((ext_vector_type(8)));
typedef float f32x2 __attribute__((ext_vector_type(2)));
typedef float f32x4 __attribute__((ext_vector_type(4)));

// async global->LDS, 16B per lane, wave-uniform LDS base + lane*16
#define GLL(g, l) __builtin_amdgcn_global_load_lds( \
    (const __attribute__((address_space(1))) void*)(g), \
    (__attribute__((address_space(3))) void*)(l), 16, 0, 0)

#define MFMA(a, b, c) __builtin_amdgcn_mfma_f32_16x16x32_bf16(a, b, c, 0, 0, 0)

__device__ __forceinline__ f32x2 unpk(unsigned int u) {
    union { unsigned int i; float f; } a, b;
    a.i = (u & 0xffffu) << 16;
    b.i = u & 0xffff0000u;
    f32x2 r; r.x = a.f; r.y = b.f; return r;
}

// fragment from swizzled LDS tile (128-B rows): elems k=l4*4+{0..3} and +16
__device__ __forceinline__ bf16x8 frag128(const char* base, int row, int cbyte) {
    const int sw = (row & 7) << 4;
    const int a = row * 128 + cbyte;
    bf16x4 lo = *(const bf16x4*)(base + (a ^ sw));
    bf16x4 hi = *(const bf16x4*)(base + ((a + 32) ^ sw));
    return __builtin_shufflevector(lo, hi, 0, 1, 2, 3, 4, 5, 6, 7);
}

// ---------------------------------------------------------------------------
// Pack kernel v3: weight transposes only (LDS-tiled, coalesced both sides).
//   0..63  : ed_w1 halves -> W1t [1024][256]
//   64..95 : ed_w2        -> W2t [256][512]
//   96..175: wr,wi,wh,f1_w,f2_w -> Wg[3][256][256], f1t, f2t
// ---------------------------------------------------------------------------
__global__ __launch_bounds__(256) void pack_kernel(
    const float* __restrict__ ed_w1, const float* __restrict__ ed_w2,
    const float* __restrict__ wr, const float* __restrict__ wi,
    const float* __restrict__ wh,
    const float* __restrict__ f1_w, const float* __restrict__ f2_w,
    bf16* __restrict__ W1t, bf16* __restrict__ W2t,
    bf16* __restrict__ Wg, bf16* __restrict__ f1t, bf16* __restrict__ f2t)
{
    const int t = blockIdx.x;
    const int tid = threadIdx.x;

    const float* src; bf16* dst; int R, C, tile;
    if (t < 64) {
        src = ed_w1 + (t >= 32 ? 131072 : 0);
        dst = W1t + (t >= 32 ? 131072 : 0);
        R = 256; C = 512; tile = t & 31;
    } else if (t < 96) {
        src = ed_w2; dst = W2t; R = 512; C = 256; tile = t - 64;
    } else {
        int m = (t - 96) >> 4; tile = (t - 96) & 15; R = 256; C = 256;
        const float* ss[5] = {wr, wi, wh, f1_w, f2_w};
        bf16* dd[5] = {Wg, Wg + 65536, Wg + 131072, f1t, f2t};
        src = ss[m]; dst = dd[m];
    }
    const int tc = C >> 6;
    const int k0 = (tile / tc) * 64, n0 = (tile % tc) * 64;

    __shared__ float ls[64][65];
    {
        int rr = tid >> 2, cc = (tid & 3) * 16;
        const float* sp = src + (size_t)(k0 + rr) * C + n0 + cc;
#pragma unroll
        for (int j = 0; j < 16; j += 4) {
            float4 v = *(const float4*)(sp + j);
            ls[rr][cc + j] = v.x; ls[rr][cc + j + 1] = v.y;
            ls[rr][cc + j + 2] = v.z; ls[rr][cc + j + 3] = v.w;
        }
    }
    __syncthreads();
    {
        int n = tid >> 2, kc = (tid & 3) * 16;
        bf16x8 o0, o1;
#pragma unroll
        for (int j = 0; j < 8; ++j) o0[j] = (bf16)ls[kc + j][n];
#pragma unroll
        for (int j = 0; j < 8; ++j) o1[j] = (bf16)ls[kc + 8 + j][n];
        bf16* dp = dst + (size_t)(n0 + n) * R + k0 + kc;
        *(bf16x8*)dp = o0;
        *(bf16x8*)(dp + 8) = o1;
    }
}

// ---------------------------------------------------------------------------
// G1: PQ = bf16( hidden @ [W1top|W1bot] ). Tile 64x64, 4 waves (2x2 of 32x32),
// BK=64, dbuf. A staged from FP32 hidden via in-kernel cvt + swizzled
// ds_write_b128 (bitwise == pre-packed bf16 path); B staged via GLL.
// ---------------------------------------------------------------------------
__global__ __launch_bounds__(256) void g1_gemm(
    const float* __restrict__ Af, const bf16* __restrict__ Bt,
    bf16* __restrict__ Cb, int N, int K)
{
    constexpr int ASZ = 64 * 64 * 2;   // 8192 B each for A and B
    __shared__ __align__(1024) char smem[4 * ASZ];

    const int tid  = threadIdx.x;
    const int wave = tid >> 6, lane = tid & 63;
    const int wr_  = wave >> 1, wc_ = wave & 1;
    const int l15  = lane & 15, l4 = lane >> 4;
    const int bm   = blockIdx.y * 64, bn = blockIdx.x * 64;

    const int srow = lane >> 3;
    const int scol = ((lane & 7) ^ (lane >> 3)) * 8;

    f32x4 acc[2][2];
#pragma unroll
    for (int mf = 0; mf < 2; ++mf)
#pragma unroll
        for (int nf = 0; nf < 2; ++nf)
            acc[mf][nf] = (f32x4){0.f, 0.f, 0.f, 0.f};

    auto stage = [&](int buf, int kt) {
        char* base = smem + buf * 2 * ASZ;
        // B: 8 segs of 1KB over 4 waves
#pragma unroll
        for (int si = 0; si < 2; ++si) {
            int s = wave * 2 + si;
            GLL(Bt + (size_t)(bn + s * 8 + srow) * K + kt * 64 + scol,
                base + ASZ + s * 1024 + lane * 16);
        }
        // A: fp32 -> bf16 cvt, swizzled ds_write_b128. 512 (row,cb) slots.
#pragma unroll
        for (int a = 0; a < 2; ++a) {
            int idx = a * 256 + tid;
            int row = idx >> 3, cb = idx & 7;
            const float* gp = Af + (size_t)(bm + row) * 256 + kt * 64 + cb * 8;
            float4 v0 = *(const float4*)gp;
            float4 v1 = *(const float4*)(gp + 4);
            bf16x8 o;
            o[0] = (bf16)v0.x; o[1] = (bf16)v0.y; o[2] = (bf16)v0.z; o[3] = (bf16)v0.w;
            o[4] = (bf16)v1.x; o[5] = (bf16)v1.y; o[6] = (bf16)v1.z; o[7] = (bf16)v1.w;
            *(bf16x8*)(base + row * 128 + ((cb ^ (row & 7)) * 16)) = o;
        }
    };

    auto compute = [&](int buf) {
        char* base = smem + buf * 2 * ASZ;
#pragma unroll
        for (int kk = 0; kk < 2; ++kk) {
            bf16x8 af[2];
#pragma unroll
            for (int mf = 0; mf < 2; ++mf)
                af[mf] = frag128(base, wr_ * 32 + mf * 16 + l15, kk * 64 + l4 * 8);
#pragma unroll
            for (int nf = 0; nf < 2; ++nf) {
                bf16x8 bfr = frag128(base + ASZ, wc_ * 32 + nf * 16 + l15, kk * 64 + l4 * 8);
#pragma unroll
                for (int mf = 0; mf < 2; ++mf)
                    acc[mf][nf] = MFMA(af[mf], bfr, acc[mf][nf]);
            }
        }
    };

    const int nt = K / 64;
    stage(0, 0);
    __syncthreads();
    for (int t = 0; t < nt; ++t) {
        if (t + 1 < nt) stage((t + 1) & 1, t + 1);
        compute(t & 1);
        __syncthreads();
    }

#pragma unroll
    for (int mf = 0; mf < 2; ++mf)
#pragma unroll
        for (int nf = 0; nf < 2; ++nf)
#pragma unroll
            for (int r = 0; r < 4; ++r) {
                int grow = bm + wr_ * 32 + mf * 16 + l4 * 4 + r;
                int col = bn + wc_ * 32 + nf * 16 + l15;
                Cb[(size_t)grow * N + col] = (bf16)acc[mf][nf][r];
            }
}

// ---------------------------------------------------------------------------
// Edge aggregation v4 (proven): packed channel pairs, 1024 blocks.
// ---------------------------------------------------------------------------
__global__ __launch_bounds__(256) void edge_agg_kernel(
    const bf16* __restrict__ PQ, const float* __restrict__ edges,
    const float* __restrict__ b1, bf16* __restrict__ S)
{
    const int blk = blockIdx.x;
    const int dgrp = blk & 15;
    const int b = blk >> 4;
    const int tid = threadIdx.x;
    const int d0 = dgrp * 4;

    __shared__ __align__(16) float wls[64][4];
    {
        int src = tid >> 2, dd = tid & 3;
        int d = d0 + dd;
        float w = 0.f;
        if (src != d) {
            int e = src * 63 + (d < src ? d : d - 1);
            float2 ev = ((const float2*)edges)[e];
            w = fmaxf(ev.x, ev.y);
        }
        wls[src][dd] = w;
    }
    __syncthreads();

    const bf16* Pb = PQ + (size_t)(b * 64) * 1024;
    f32x2 p2[4];
#pragma unroll
    for (int dd = 0; dd < 4; ++dd)
        p2[dd] = unpk(*(const unsigned int*)(Pb + (size_t)(d0 + dd) * 1024 + 2 * tid));
    float2 bbl = *(const float2*)(b1 + 2 * tid);
    f32x2 bb; bb.x = bbl.x; bb.y = bbl.y;
    const unsigned int* Qp = (const unsigned int*)(Pb + 512) + tid;

    f32x2 acc[4];
#pragma unroll
    for (int dd = 0; dd < 4; ++dd) acc[dd] = (f32x2){0.f, 0.f};

#pragma unroll 4
    for (int src = 0; src < 64; ++src) {
        f32x2 q = unpk(Qp[(size_t)src * 512]);
        float4 wv = *(const float4*)&wls[src][0];
        float w[4] = {wv.x, wv.y, wv.z, wv.w};
#pragma unroll
        for (int dd = 0; dd < 4; ++dd) {
            f32x2 w2; w2.x = w[dd]; w2.y = w[dd];
            f32x2 v = (p2[dd] + q) * w2 + bb;
            float e0 = __expf(v.x) - 1.f;
            float e1 = __expf(v.y) - 1.f;
            f32x2 r;
            r.x = (v.x > 0.f) ? v.x : e0;
            r.y = (v.y > 0.f) ? v.y : e1;
            acc[dd] += r;
        }
    }
    f32x2 selfc;
    selfc.x = (bb.x > 0.f) ? bb.x : (__expf(bb.x) - 1.f);
    selfc.y = (bb.y > 0.f) ? bb.y : (__expf(bb.y) - 1.f);
#pragma unroll
    for (int dd = 0; dd < 4; ++dd) {
        bf16x2 st;
        st[0] = (bf16)(acc[dd].x - selfc.x);
        st[1] = (bf16)(acc[dd].y - selfc.y);
        *(bf16x2*)(S + (size_t)(b * 64 + d0 + dd) * 512 + 2 * tid) = st;
    }
}

// ---------------------------------------------------------------------------
// Small MFMA GEMM: tile 32x64, 4 waves (2x2) of 16x32, BK=64, dbuf, GLL.
// Grid (N/64, M/32) = 512 blocks -> 2 blocks/CU (drain overlap).
// MODE 1: Cb = bf16(A@B*scale + bias)
// MODE 2: Cb = bf16(relu(A@B + bias))
// MODE 3: 3 B-matrices + fused GRU -> Cf=NH fp32, Cb=NH bf16
// ---------------------------------------------------------------------------
template<int MODE>
__global__ __launch_bounds__(256) void small_gemm(
    const bf16* __restrict__ A, const bf16* __restrict__ Bt,
    const float* __restrict__ bias,
    float* __restrict__ Cf, bf16* __restrict__ Cb,
    int N, int K, float scale,
    const float* __restrict__ inputs, const float* __restrict__ hidden,
    const float* __restrict__ irw, const float* __restrict__ irb,
    const float* __restrict__ iiw, const float* __restrict__ iib,
    const float* __restrict__ inw, const float* __restrict__ inb)
{
    constexpr int NB  = (MODE == 3) ? 3 : 1;
    constexpr int ASZ = 32 * 64 * 2;        // 4096 B
    constexpr int BSZ = 64 * 64 * 2 * NB;   // 8192*NB
    __shared__ __align__(1024) char smem[2 * (ASZ + BSZ)];

    const int tid  = threadIdx.x;
    const int wave = tid >> 6, lane = tid & 63;
    const int wr_  = wave >> 1, wc_ = wave & 1;
    const int l15  = lane & 15, l4 = lane >> 4;
    const int bm   = blockIdx.y * 32, bn = blockIdx.x * 64;

    const int srow = lane >> 3;
    const int scol = ((lane & 7) ^ (lane >> 3)) * 8;

    f32x4 acc[NB][2];
#pragma unroll
    for (int g = 0; g < NB; ++g)
#pragma unroll
        for (int nf = 0; nf < 2; ++nf)
            acc[g][nf] = (f32x4){0.f, 0.f, 0.f, 0.f};

    constexpr int per = (4 + 8 * NB) / 4;   // segs/wave: 3 (NB=1), 7 (NB=3)

    auto stage = [&](int buf, int kt) {
        char* base = smem + buf * (ASZ + BSZ);
#pragma unroll
        for (int si = 0; si < per; ++si) {
            int s = wave * per + si;
            char* ldst = base + s * 1024 + lane * 16;
            const bf16* g;
            if (s < 4) {
                g = A + ((size_t)(bm + s * 8 + srow) * K + kt * 64 + scol);
            } else {
                int sb = s - 4;
                int gi = sb >> 3, r8 = sb & 7;
                g = Bt + (size_t)gi * 256 * K
                      + (size_t)(bn + r8 * 8 + srow) * K + kt * 64 + scol;
            }
            GLL(g, ldst);
        }
    };

    auto compute = [&](int buf) {
        char* base = smem + buf * (ASZ + BSZ);
#pragma unroll
        for (int kk = 0; kk < 2; ++kk) {
            bf16x8 af = frag128(base, wr_ * 16 + l15, kk * 64 + l4 * 8);
#pragma unroll
            for (int g = 0; g < NB; ++g)
#pragma unroll
                for (int nf = 0; nf < 2; ++nf) {
                    bf16x8 bfr = frag128(base + ASZ + g * 8192,
                                         wc_ * 32 + nf * 16 + l15, kk * 64 + l4 * 8);
                    acc[g][nf] = MFMA(af, bfr, acc[g][nf]);
                }
        }
    };

    const int nt = K / 64;
    stage(0, 0);
    __syncthreads();
    for (int t = 0; t < nt; ++t) {
        if (t + 1 < nt) stage((t + 1) & 1, t + 1);
        compute(t & 1);
        __syncthreads();
    }

    if constexpr (MODE == 3) {
#pragma unroll
        for (int nf = 0; nf < 2; ++nf) {
            const int col = bn + wc_ * 32 + nf * 16 + l15;
            float w8r[8], w8i[8], w8n[8];
#pragma unroll
            for (int f = 0; f < 8; ++f) {
                w8r[f] = irw[f * 256 + col];
                w8i[f] = iiw[f * 256 + col];
                w8n[f] = inw[f * 256 + col];
            }
            const float xr0 = irb[col], xi0 = iib[col], xn0 = inb[col];
#pragma unroll
            for (int r = 0; r < 4; ++r) {
                const int grow = bm + wr_ * 16 + l4 * 4 + r;
                const float* inp = inputs + (size_t)grow * 8;
                float xr = xr0, xi = xi0, xn = xn0;
#pragma unroll
                for (int f = 0; f < 8; ++f) {
                    float x = inp[f];
                    xr += x * w8r[f]; xi += x * w8i[f]; xn += x * w8n[f];
                }
                float aR = acc[0][nf][r];
                float aI = acc[1][nf][r];
                float aN = acc[2][nf][r];
                float rg = __builtin_amdgcn_rcpf(1.f + __expf(-(xr + aR)));
                float ig = __builtin_amdgcn_rcpf(1.f + __expf(-(xi + aI)));
                float tz = xn + rg * aN;
                tz = fminf(fmaxf(tz, -15.f), 15.f);
                float e2x = __expf(2.f * tz);
                float nn = (e2x - 1.f) * __builtin_amdgcn_rcpf(e2x + 1.f);
                size_t o = (size_t)grow * 256 + col;
                float nh = (1.f - ig) * nn + ig * hidden[o];
                Cf[o] = nh;
                Cb[o] = (bf16)nh;
            }
        }
    } else {
#pragma unroll
        for (int nf = 0; nf < 2; ++nf)
#pragma unroll
            for (int r = 0; r < 4; ++r) {
                int grow = bm + wr_ * 16 + l4 * 4 + r;
                int col = bn + wc_ * 32 + nf * 16 + l15;
                float v = acc[0][nf][r];
                if constexpr (MODE == 1) v = v * scale + bias[col];
                if constexpr (MODE == 2) v = fmaxf(v + bias[col], 0.f);
                Cb[(size_t)grow * N + col] = (bf16)v;
            }
    }
}

// ---------------------------------------------------------------------------
// pred[row,f] = inputs[row,f] + H2[row,:] @ f3_w[:,f] + f3_b[f]
// ---------------------------------------------------------------------------
__global__ __launch_bounds__(256) void pred_kernel(
    const float* __restrict__ inputs, const bf16* __restrict__ H2,
    const float* __restrict__ f3_w, const float* __restrict__ f3_b,
    float* __restrict__ pred)
{
    __shared__ float f3s[2048];
    for (int i = threadIdx.x; i < 2048; i += 256) f3s[i] = f3_w[i];
    __syncthreads();

    const int idx = blockIdx.x * 256 + threadIdx.x;
    const int row = idx >> 3, f = idx & 7;
    const bf16* hr = H2 + (size_t)row * 256;
    float a = f3_b[f];
    for (int k0 = 0; k0 < 256; k0 += 8) {
        bf16x8 h8 = *(const bf16x8*)(hr + k0);
#pragma unroll
        for (int j = 0; j < 8; ++j)
            a += (float)h8[j] * f3s[(k0 + j) * 8 + f];
    }
    pred[idx] = inputs[idx] + a;
}

// ---------------------------------------------------------------------------
extern "C" void kernel_launch(void* const* d_in, const int* in_sizes, int n_in,
                              void* d_out, int out_size, void* d_ws, size_t ws_size,
                              hipStream_t stream) {
    const float* inputs = (const float*)d_in[0];
    const float* hidden = (const float*)d_in[1];
    const float* edges  = (const float*)d_in[2];
    const float* ed_w1 = (const float*)d_in[4];
    const float* ed_b1 = (const float*)d_in[5];
    const float* ed_w2 = (const float*)d_in[6];
    const float* ed_b2 = (const float*)d_in[7];
    const float* wr = (const float*)d_in[8];
    const float* wi = (const float*)d_in[9];
    const float* wh = (const float*)d_in[10];
    const float* ir_w = (const float*)d_in[11];
    const float* ir_b = (const float*)d_in[12];
    const float* ii_w = (const float*)d_in[13];
    const float* ii_b = (const float*)d_in[14];
    const float* in_w = (const float*)d_in[15];
    const float* in_b = (const float*)d_in[16];
    const float* f1_w = (const float*)d_in[17];
    const float* f1_b = (const float*)d_in[18];
    const float* f2_w = (const float*)d_in[19];
    const float* f2_b = (const float*)d_in[20];
    const float* f3_w = (const float*)d_in[21];
    const float* f3_b = (const float*)d_in[22];

    float* out = (float*)d_out;
    float* pred = out;
    float* NH = out + (size_t)BB * NN * FF;

    // bf16 workspace layout (element offsets)
    bf16* bws = (bf16*)d_ws;
    bf16* PQ   = bws;              // 4096*1024
    bf16* Sb   = bws + 4194304;    // 4096*512
    bf16* AGGb = bws + 6291456;    // 4096*256
    bf16* NHb  = bws + 7340032;    // 4096*256
    bf16* H1b  = bws + 8388608;    // 4096*256
    bf16* H2b  = bws + 9437184;    // 4096*256
    bf16* W1t  = bws + 10485760;   // 1024*256
    bf16* W2t  = bws + 10747904;   // 256*512
    bf16* Wg   = bws + 10878976;   // 3*256*256
    bf16* f1t  = bws + 11075584;   // 256*256
    bf16* f2t  = bws + 11141120;   // 256*256

    dim3 blk(256);

    pack_kernel<<<dim3(176), blk, 0, stream>>>(
        ed_w1, ed_w2, wr, wi, wh, f1_w, f2_w,
        W1t, W2t, Wg, f1t, f2t);

    // G1: PQ = hidden @ [W1top | W1bot]   (4096,1024,256), fp32 A in-kernel cvt
    g1_gemm<<<dim3(16, 64), blk, 0, stream>>>(hidden, W1t, PQ, 1024, 256);

    // S: per-(b,d) elu-sum over sources
    edge_agg_kernel<<<dim3(1024), blk, 0, stream>>>(PQ, edges, ed_b1, Sb);

    // G2: agg = S @ ed_w2 / 63 + ed_b2    (4096,256,512)
    small_gemm<1><<<dim3(4, 128), blk, 0, stream>>>(
        Sb, W2t, ed_b2, nullptr, AGGb, 256, 512, 1.f / 63.f,
        nullptr, nullptr, nullptr, nullptr, nullptr, nullptr, nullptr, nullptr);

    // G3: gates + fused GRU -> NH (fp32) + NHb (bf16)
    small_gemm<3><<<dim3(4, 128), blk, 0, stream>>>(
        AGGb, Wg, nullptr, NH, NHb, 256, 256, 1.f,
        inputs, hidden, ir_w, ir_b, ii_w, ii_b, in_w, in_b);

    // f1, f2 (relu)
    small_gemm<2><<<dim3(4, 128), blk, 0, stream>>>(
        NHb, f1t, f1_b, nullptr, H1b, 256, 256, 1.f,
        nullptr, nullptr, nullptr, nullptr, nullptr, nullptr, nullptr, nullptr);
    small_gemm<2><<<dim3(4, 128), blk, 0, stream>>>(
        H1b, f2t, f2_b, nullptr, H2b, 256, 256, 1.f,
        nullptr, nullptr, nullptr, nullptr, nullptr, nullptr, nullptr, nullptr);

    pred_kernel<<<dim3(128), blk, 0, stream>>>(inputs, H2b, f3_w, f3_b, pred);
}